// Round 2
// baseline (814.181 us; speedup 1.0000x reference)
//
#include <hip/hip_runtime.h>

// Kalman filter: B=4096, T=200, S=8, M=2.
// Decomposition: 8 lanes per batch element (lane r owns cov row r; mean replicated),
// 8 batch elements per wave, 512 blocks x 64 threads = 512 waves.
// All cross-lane via __shfl within width-8 groups. Sequential scan over t in-kernel.

namespace {
constexpr int S = 8;
constexpr int T = 200;
constexpr int B = 4096;
}

__global__ __launch_bounds__(64)
void kf_kernel(const float* __restrict__ yg,   // [B,T,2]
               const float* __restrict__ Fg,   // [B,T,8,8]
               const float* __restrict__ Hg,   // [B,T,2,8]
               const float* __restrict__ Qg,   // [8,8]
               const float* __restrict__ Rg,   // [2,2]
               const float* __restrict__ img,  // [B,8]
               const float* __restrict__ icg,  // [8,8]
               float* __restrict__ means,      // [B,T,8]
               float* __restrict__ covs)       // [B,T,8,8]
{
    const int lane = threadIdx.x;       // 0..63
    const int g    = lane >> 3;         // group within wave
    const int r    = lane & 7;          // row owned by this lane
    const int b    = (blockIdx.x << 3) + g;

    // constants
    float Qrow[8];
#pragma unroll
    for (int j = 0; j < 8; ++j) Qrow[j] = Qg[r * 8 + j];
    const float R00 = Rg[0], R01 = Rg[1], R11 = Rg[3];

    // state: P = cov row r; mu = full mean (replicated); mur = mean[r] (lane-own scalar)
    float P[8];
#pragma unroll
    for (int j = 0; j < 8; ++j) P[j] = icg[r * 8 + j];
    float mu[8];
#pragma unroll
    for (int j = 0; j < 8; ++j) mu[j] = img[b * 8 + j];
    float mur = img[b * 8 + r];

    float* mout  = means + (size_t)b * T * 8;
    float* cout_ = covs  + (size_t)b * T * 64;

    // t = 0 outputs (initial state)
    mout[r] = mur;
    {
        float4* cp = reinterpret_cast<float4*>(cout_ + r * 8);
        cp[0] = make_float4(P[0], P[1], P[2], P[3]);
        cp[1] = make_float4(P[4], P[5], P[6], P[7]);
    }

    const float* Fb = Fg + (size_t)b * T * 64 + r * 8;  // this lane's F row
    const float* Hb = Hg + (size_t)b * T * 16;          // full H (replicated load, L1-served)
    const float* yb = yg + (size_t)b * T * 2;

    // prefetch t = 0
    float4 f0 = *reinterpret_cast<const float4*>(Fb);
    float4 f1 = *reinterpret_cast<const float4*>(Fb + 4);
    float4 ha = *reinterpret_cast<const float4*>(Hb);
    float4 hb = *reinterpret_cast<const float4*>(Hb + 4);
    float4 hc = *reinterpret_cast<const float4*>(Hb + 8);
    float4 hd = *reinterpret_cast<const float4*>(Hb + 12);
    float2 yv = *reinterpret_cast<const float2*>(yb);

    for (int t = 0; t < T - 1; ++t) {
        const float Fr[8]  = {f0.x, f0.y, f0.z, f0.w, f1.x, f1.y, f1.z, f1.w};
        const float h0v[8] = {ha.x, ha.y, ha.z, ha.w, hb.x, hb.y, hb.z, hb.w};
        const float h1v[8] = {hc.x, hc.y, hc.z, hc.w, hd.x, hd.y, hd.z, hd.w};
        const float y0 = yv.x, y1 = yv.y;

        // prefetch t+1 (t+1 <= 199 is in-bounds; last prefetch simply unused)
        {
            const float* Fp = Fb + (size_t)(t + 1) * 64;
            f0 = *reinterpret_cast<const float4*>(Fp);
            f1 = *reinterpret_cast<const float4*>(Fp + 4);
            const float* Hp = Hb + (size_t)(t + 1) * 16;
            ha = *reinterpret_cast<const float4*>(Hp);
            hb = *reinterpret_cast<const float4*>(Hp + 4);
            hc = *reinterpret_cast<const float4*>(Hp + 8);
            hd = *reinterpret_cast<const float4*>(Hp + 12);
            yv = *reinterpret_cast<const float2*>(yb + (size_t)(t + 1) * 2);
        }

        // innovation z = H mu (local: mu replicated); hp = (H P)[:, r] via P symmetry
        float z0 = 0.f, z1 = 0.f, hp0 = 0.f, hp1 = 0.f;
#pragma unroll
        for (int j = 0; j < 8; ++j) {
            z0  = fmaf(h0v[j], mu[j], z0);
            z1  = fmaf(h1v[j], mu[j], z1);
            hp0 = fmaf(h0v[j], P[j], hp0);
            hp1 = fmaf(h1v[j], P[j], hp1);
        }
        const float r0 = y0 - z0, r1 = y1 - z1;

        // broadcast hp across the group -> full HP rows on every lane
        float hp0v[8], hp1v[8];
#pragma unroll
        for (int s = 0; s < 8; ++s) {
            hp0v[s] = __shfl(hp0, s, 8);
            hp1v[s] = __shfl(hp1, s, 8);
        }

        // S = H P H^T + R (local dots of replicated vectors)
        float S00 = R00, S01 = R01, S11 = R11;
#pragma unroll
        for (int j = 0; j < 8; ++j) {
            S00 = fmaf(hp0v[j], h0v[j], S00);
            S01 = fmaf(hp0v[j], h1v[j], S01);
            S11 = fmaf(hp1v[j], h1v[j], S11);
        }

        // 2x2 solve: K row r = S^{-1} hp (S symmetric)
        const float det  = fmaf(S00, S11, -S01 * S01);
        const float rdet = 1.0f / det;
        const float i00 = S11 * rdet, i01 = -S01 * rdet, i11 = S00 * rdet;
        const float k0 = fmaf(i00, hp0, i01 * hp1);
        const float k1 = fmaf(i01, hp0, i11 * hp1);

        // broadcast K
        float kb0[8], kb1[8];
#pragma unroll
        for (int s = 0; s < 8; ++s) {
            kb0[s] = __shfl(k0, s, 8);
            kb1[s] = __shfl(k1, s, 8);
        }

        // mean update (replicated) + lane-own scalar
#pragma unroll
        for (int i = 0; i < 8; ++i) mu[i] = fmaf(kb0[i], r0, fmaf(kb1[i], r1, mu[i]));
        mur = fmaf(k0, r0, fmaf(k1, r1, mur));

        // Joseph covariance update, algebraically expanded (exact identity):
        // U = P - K*HP - (K*HP)^T + K S K^T
        const float e0 = fmaf(k0, S00, k1 * S01);
        const float e1 = fmaf(k0, S01, k1 * S11);
        const float g0 = e0 - hp0, g1 = e1 - hp1;
        float U[8];
#pragma unroll
        for (int j = 0; j < 8; ++j) {
            float u = P[j];
            u = fmaf(-k0, hp0v[j], u);
            u = fmaf(-k1, hp1v[j], u);
            u = fmaf(g0, kb0[j], u);
            u = fmaf(g1, kb1[j], u);
            U[j] = u;
        }

        // predict: v = F[r,:] @ U   (U rows broadcast, consumed on the fly)
        float v[8] = {0.f, 0.f, 0.f, 0.f, 0.f, 0.f, 0.f, 0.f};
#pragma unroll
        for (int s = 0; s < 8; ++s) {
            const float fs = Fr[s];
#pragma unroll
            for (int k = 0; k < 8; ++k)
                v[k] = fmaf(fs, __shfl(U[k], s, 8), v[k]);
        }

        // single F-broadcast pass serves both mean_p and cov_p row r
        float Pn[8], nmu[8];
#pragma unroll
        for (int jc = 0; jc < 8; ++jc) {
            float a = 0.f, c = 0.f;
#pragma unroll
            for (int k = 0; k < 8; ++k) {
                const float bF = __shfl(Fr[k], jc, 8);
                a = fmaf(bF, mu[k], a);   // mean_p[jc] = F[jc,:] . mean_u
                c = fmaf(v[k], bF, c);    // cov_p[r][jc] = v . F[jc,:]
            }
            nmu[jc] = a;
            Pn[jc]  = c + Qrow[jc];
        }
        // lane-own mean_p[r] via local F row (avoids dynamic index nmu[r])
        float murp = 0.f;
#pragma unroll
        for (int k = 0; k < 8; ++k) murp = fmaf(Fr[k], mu[k], murp);
        mur = murp;
#pragma unroll
        for (int i = 0; i < 8; ++i) { mu[i] = nmu[i]; P[i] = Pn[i]; }

        // store outputs at ts = t+1
        mout[(t + 1) * 8 + r] = mur;
        float4* cp = reinterpret_cast<float4*>(cout_ + (size_t)(t + 1) * 64 + r * 8);
        cp[0] = make_float4(P[0], P[1], P[2], P[3]);
        cp[1] = make_float4(P[4], P[5], P[6], P[7]);
    }
}

extern "C" void kernel_launch(void* const* d_in, const int* in_sizes, int n_in,
                              void* d_out, int out_size, void* d_ws, size_t ws_size,
                              hipStream_t stream) {
    const float* y  = (const float*)d_in[0];
    const float* F  = (const float*)d_in[1];
    const float* H  = (const float*)d_in[2];
    const float* Q  = (const float*)d_in[3];
    const float* R  = (const float*)d_in[4];
    const float* im = (const float*)d_in[5];
    const float* ic = (const float*)d_in[6];
    // d_in[7] = n_step (always 1)

    float* means = (float*)d_out;
    float* covs  = means + (size_t)B * T * S;

    dim3 grid(B / 8), block(64);
    hipLaunchKernelGGL(kf_kernel, grid, block, 0, stream,
                       y, F, H, Q, R, im, ic, means, covs);
}